// Round 8
// baseline (231.523 us; speedup 1.0000x reference)
//
#include <hip/hip_runtime.h>

// C = tril(tril(A) @ tril(B)), N=4096, fp32 in/out.
// Round 8: round-7 + counted-vmcnt 3-buffer pipeline in the GEMM k-loop (T4).
//   Per step: s_waitcnt vmcnt(4) -> raw s_barrier -> STAGE(t+2) -> ds_read/MFMA.
//   Prefetched loads stay in flight ACROSS barriers (never drained to 0 in the
//   main loop); epilogue step drains with vmcnt(0).
//   Everything else identical to round 7 (verified): memset C, bf16 planes,
//   split-K (>64 k-tiles -> 2 segments, atomicAdd), both-sides XOR swizzle.

typedef __attribute__((ext_vector_type(8))) short short8;   // 8 bf16 (4 VGPR)
typedef __attribute__((ext_vector_type(4))) float f32x4;
typedef __attribute__((ext_vector_type(2))) unsigned int u32x2;
typedef __attribute__((ext_vector_type(4))) unsigned int u32x4;

constexpr int N_DIM = 4096;
constexpr int BM = 128, BN = 128, BK = 32;
constexpr int NT = N_DIM / BM;             // 32
constexpr int N_LOWER = NT * (NT + 1) / 2; // 528

__device__ __forceinline__ unsigned bf16_rne(float x) {
    const unsigned u = __float_as_uint(x);
    return (u + 0x7FFFu + ((u >> 16) & 1u)) >> 16;
}
__device__ __forceinline__ void split2(float x, unsigned& h, unsigned& l) {
    h = bf16_rne(x);
    const float r = x - __uint_as_float(h << 16);
    l = __float_as_uint(r) >> 16;
}
__device__ __forceinline__ void gload_lds16(const void* g, void* l) {
    __builtin_amdgcn_global_load_lds(
        (const __attribute__((address_space(1))) void*)g,
        (__attribute__((address_space(3))) void*)l, 16, 0, 0);
}

// ---------------- P1: Ah = bf16(tril(A)), row-major, lower tiles ----------------
__global__ __launch_bounds__(256)
void split_A1(const float* __restrict__ A, unsigned short* __restrict__ Ah) {
    const int id = blockIdx.x;
    int ti = (int)((sqrtf(8.f * (float)id + 1.f) - 1.f) * 0.5f);
    ti = ti < 0 ? 0 : (ti > NT - 1 ? NT - 1 : ti);
    while (ti * (ti + 1) / 2 > id) --ti;
    while ((ti + 1) * (ti + 2) / 2 <= id) ++ti;
    const int tk = id - ti * (ti + 1) / 2;          // tk <= ti
    const int r0 = ti * 128, k0 = tk * 128;
    const bool dg = (ti == tk);
    const int tid = threadIdx.x;
    #pragma unroll
    for (int it = 0; it < 16; ++it) {
        const int f = it * 256 + tid;
        const int row = f >> 5, c4 = (f & 31) * 4;
        const int i = r0 + row;
        const size_t off = (size_t)i * N_DIM + k0 + c4;
        float4 v = *reinterpret_cast<const float4*>(&A[off]);
        if (dg) {
            if (k0 + c4 + 0 > i) v.x = 0.f;
            if (k0 + c4 + 1 > i) v.y = 0.f;
            if (k0 + c4 + 2 > i) v.z = 0.f;
            if (k0 + c4 + 3 > i) v.w = 0.f;
        }
        *reinterpret_cast<u32x2*>(&Ah[off]) =
            (u32x2){bf16_rne(v.x) | (bf16_rne(v.y) << 16),
                    bf16_rne(v.z) | (bf16_rne(v.w) << 16)};
    }
}

// ------------- P2: Bt = bf16(tril(B))^T [col][k], needed 64-tiles only ----------
__global__ __launch_bounds__(256)
void split_Bt1(const float* __restrict__ B, unsigned short* __restrict__ Bt) {
    const int tk = blockIdx.x, tj = blockIdx.y;     // 64-elem tiles
    if (tk < (tj & ~1)) return;                     // never read by GEMM
    const int k0 = tk * 64, j0 = tj * 64;
    const int tid = threadIdx.x;
    __shared__ float T[64][69];                     // [col][k], padded
    #pragma unroll
    for (int it = 0; it < 4; ++it) {
        const int f = it * 256 + tid;
        const int kr = f >> 4, c4 = (f & 15) * 4;
        const float4 v = *reinterpret_cast<const float4*>(
            &B[(size_t)(k0 + kr) * N_DIM + j0 + c4]);
        T[c4 + 0][kr] = v.x; T[c4 + 1][kr] = v.y;
        T[c4 + 2][kr] = v.z; T[c4 + 3][kr] = v.w;
    }
    __syncthreads();
    #pragma unroll
    for (int it = 0; it < 2; ++it) {
        const int f = it * 256 + tid;
        const int col = f >> 3, kc = (f & 7) * 8;
        const int j = j0 + col;
        unsigned h[8];
        #pragma unroll
        for (int e = 0; e < 8; ++e) {
            float x = T[col][kc + e];
            if (j > k0 + kc + e) x = 0.f;           // tril(B): keep j<=k
            h[e] = bf16_rne(x);
        }
        *reinterpret_cast<u32x4*>(&Bt[(size_t)j * N_DIM + k0 + kc]) =
            (u32x4){h[0] | (h[1] << 16), h[2] | (h[3] << 16),
                    h[4] | (h[5] << 16), h[6] | (h[7] << 16)};
    }
}

// -------- G: split-K, 3-buffer counted-vmcnt pipelined bf16 MFMA GEMM -----------
__global__ __launch_bounds__(256)
void trimm_seg(const unsigned short* __restrict__ Ah,
               const unsigned short* __restrict__ Bt,
               float* __restrict__ C) {
    const int tid = threadIdx.x;
    const int idx = blockIdx.x;                     // 0..527, heavy-first
    const int seg = blockIdx.y;                     // 0..1

    // heavy-first: dr=0 -> farthest-from-diagonal first
    int dr = (int)((sqrtf(8.f * (float)idx + 1.f) - 1.f) * 0.5f);
    dr = dr < 0 ? 0 : (dr > NT - 1 ? NT - 1 : dr);
    while (dr * (dr + 1) / 2 > idx) --dr;
    while ((dr + 1) * (dr + 2) / 2 <= idx) ++dr;
    const int bj = idx - dr * (dr + 1) / 2;
    const int bi = bj + (NT - 1 - dr);
    const int r0 = bi * BM, c0 = bj * BN;

    const int kt0 = bj * (BN / BK);
    const int kt1 = (bi + 1) * (BM / BK);
    const int len = kt1 - kt0;                      // 4..128 k-tiles
    const int nseg = (len > 64) ? 2 : 1;
    if (seg >= nseg) return;
    int s0 = kt0, s1 = kt1;
    if (nseg == 2) {
        const int mid = kt0 + (len >> 1);
        if (seg == 0) s1 = mid; else s0 = mid;
    }
    // segment length always >= 2 (min tile len = 4)

    __shared__ __align__(16) unsigned short sA[3][BM * BK];   // 3 x 8 KB
    __shared__ __align__(16) unsigned short sB[3][BN * BK];   // 3 x 8 KB

    const int lane = tid & 63, w = tid >> 6;
    const int wm = w >> 1, wn = w & 1;
    const int l15 = lane & 15, l4 = lane >> 4;

    f32x4 acc[4][4];
    #pragma unroll
    for (int m = 0; m < 4; ++m)
        #pragma unroll
        for (int n = 0; n < 4; ++n) acc[m][n] = (f32x4){0.f, 0.f, 0.f, 0.f};

    // STAGE(buf, kt): LDS dest linear; source pre-swizzled (involution), so
    // the XOR'd ds_read below sees G[r][s]. 4 gload_lds per thread per STAGE.
    #define STAGE(buf, kt)                                                        \
        {                                                                         \
            _Pragma("unroll")                                                     \
            for (int g = 0; g < 2; ++g) {                                         \
                const int c = g * 256 + tid;                                      \
                const int row = c >> 2;                                           \
                const int srcslot = (c ^ (row >> 1)) & 3;                         \
                const int ldst = (g * 256 + (tid & 192)) * 8;                     \
                gload_lds16(&Ah[(size_t)(r0 + row) * N_DIM + (kt) * BK + srcslot * 8], \
                            &sA[buf][ldst]);                                      \
                gload_lds16(&Bt[(size_t)(c0 + row) * N_DIM + (kt) * BK + srcslot * 8], \
                            &sB[buf][ldst]);                                      \
            }                                                                     \
        }

    // COMPUTE(buf): XOR'd conflict-free b128 fragment reads + 16 MFMA
    #define COMPUTE(buf)                                                          \
        {                                                                         \
            short8 a[4], b[4];                                                    \
            _Pragma("unroll")                                                     \
            for (int m = 0; m < 4; ++m) {                                         \
                const int r = wm * 64 + m * 16 + l15;                             \
                a[m] = *reinterpret_cast<const short8*>(                          \
                    &sA[buf][r * 32 + (((l4 ^ (r >> 1)) & 3) * 8)]);              \
            }                                                                     \
            _Pragma("unroll")                                                     \
            for (int n = 0; n < 4; ++n) {                                         \
                const int cl = wn * 64 + n * 16 + l15;                            \
                b[n] = *reinterpret_cast<const short8*>(                          \
                    &sB[buf][cl * 32 + (((l4 ^ (cl >> 1)) & 3) * 8)]);            \
            }                                                                     \
            _Pragma("unroll")                                                     \
            for (int m = 0; m < 4; ++m)                                           \
                _Pragma("unroll")                                                 \
                for (int n = 0; n < 4; ++n)                                       \
                    acc[m][n] = __builtin_amdgcn_mfma_f32_16x16x32_bf16(          \
                        a[m], b[n], acc[m][n], 0, 0, 0);                          \
        }

    // prologue: 2 STAGEs in flight (8 outstanding loads per thread)
    STAGE(0, s0);
    STAGE(1, s0 + 1);

    int cur = 0;
    for (int t = s0; t < s1 - 1; ++t) {
        // wait own STAGE(t) landed (STAGE(t+1)'s 4 loads stay in flight) ...
        asm volatile("s_waitcnt vmcnt(4)" ::: "memory");
        // ... then barrier: all waves' STAGE(t) visible, and all waves are
        // done reading buf[(t-1)%3] (consumed before their prior MFMAs).
        __builtin_amdgcn_s_barrier();
        // safe to overwrite buf[(t+2)%3] == buf[(t-1)%3] now
        if (t + 2 < s1) {
            int b2 = cur + 2; if (b2 >= 3) b2 -= 3;
            STAGE(b2, t + 2);
        }
        COMPUTE(cur);
        ++cur; if (cur == 3) cur = 0;
    }
    // epilogue step t = s1-1: drain remaining loads
    asm volatile("s_waitcnt vmcnt(0)" ::: "memory");
    __builtin_amdgcn_s_barrier();
    COMPUTE(cur);
    #undef STAGE
    #undef COMPUTE

    // epilogue: C/D layout col=l&15, row=(l>>4)*4+reg (m89-verified)
    if (nseg == 1) {
        const bool diag = (bi == bj);
        #pragma unroll
        for (int m = 0; m < 4; ++m) {
            const int i0 = r0 + wm * 64 + m * 16 + l4 * 4;
            #pragma unroll
            for (int n = 0; n < 4; ++n) {
                const int j = c0 + wn * 64 + n * 16 + l15;
                #pragma unroll
                for (int r = 0; r < 4; ++r) {
                    float val = acc[m][n][r];
                    if (diag && (j > i0 + r)) val = 0.f;
                    C[(size_t)(i0 + r) * N_DIM + j] = val;
                }
            }
        }
    } else {
        // 2 segments, C pre-zeroed: exactly 2 fp32 adds/element (deterministic)
        #pragma unroll
        for (int m = 0; m < 4; ++m) {
            const int i0 = r0 + wm * 64 + m * 16 + l4 * 4;
            #pragma unroll
            for (int n = 0; n < 4; ++n) {
                const int j = c0 + wn * 64 + n * 16 + l15;
                #pragma unroll
                for (int r = 0; r < 4; ++r)
                    atomicAdd(&C[(size_t)(i0 + r) * N_DIM + j], acc[m][n][r]);
            }
        }
    }
}

// ---------------- fallback: round-3 kernel (in-loop split bf16x3), verified -----
constexpr int LP = 40;
__global__ __launch_bounds__(256)
void trimm_fallback(const float* __restrict__ A, const float* __restrict__ B,
                    float* __restrict__ C) {
    const int tid = threadIdx.x;
    const int id = blockIdx.x;
    if (id >= N_LOWER) {
        int u = id - N_LOWER, bi = 0;
        while (u >= NT - 1 - bi) { u -= NT - 1 - bi; ++bi; }
        const int bj = bi + 1 + u;
        const int r0 = bi * BM, c0 = bj * BN;
        const float4 z = make_float4(0.f, 0.f, 0.f, 0.f);
        #pragma unroll
        for (int r = 0; r < 16; ++r) {
            const int f = r * 256 + tid;
            *reinterpret_cast<float4*>(
                &C[(size_t)(r0 + (f >> 5)) * N_DIM + c0 + (f & 31) * 4]) = z;
        }
        return;
    }
    int dr = (int)((sqrtf(8.f * (float)id + 1.f) - 1.f) * 0.5f);
    dr = dr < 0 ? 0 : (dr > NT - 1 ? NT - 1 : dr);
    while (dr * (dr + 1) / 2 > id) --dr;
    while ((dr + 1) * (dr + 2) / 2 <= id) ++dr;
    const int bj = id - dr * (dr + 1) / 2;
    const int bi = bj + (NT - 1 - dr);
    const int r0 = bi * BM, c0 = bj * BN;

    __shared__ __align__(16) unsigned short AsH[BM][LP];
    __shared__ __align__(16) unsigned short AsL[BM][LP];
    __shared__ __align__(16) unsigned short BsH[BN][LP];
    __shared__ __align__(16) unsigned short BsL[BN][LP];

    const int lane = tid & 63, w = tid >> 6;
    const int wm = w >> 1, wn = w & 1;
    const int l15 = lane & 15, l4 = lane >> 4;

    f32x4 acc[4][4];
    #pragma unroll
    for (int m = 0; m < 4; ++m)
        #pragma unroll
        for (int n = 0; n < 4; ++n) acc[m][n] = (f32x4){0.f, 0.f, 0.f, 0.f};

    const int kt0 = bj * (BN / BK);
    const int kt1 = (bi + 1) * (BM / BK);
    const int ktA = bi * (BM / BK);
    const int ktB = (bj + 1) * (BN / BK);

    for (int kt = kt0; kt < kt1; ++kt) {
        const int k0 = kt * BK;
        __syncthreads();
        float4 ga[4]; float gb[4][4];
        #pragma unroll
        for (int r = 0; r < 4; ++r) {
            const int f = r * 256 + tid;
            ga[r] = *reinterpret_cast<const float4*>(
                &A[(size_t)(r0 + (f >> 3)) * N_DIM + k0 + (f & 7) * 4]);
        }
        #pragma unroll
        for (int r = 0; r < 4; ++r) {
            const int f = r * 256 + tid;
            const int col = f & 127, kq = (f >> 7) * 4;
            const float* bp = &B[(size_t)(k0 + kq) * N_DIM + c0 + col];
            #pragma unroll
            for (int e = 0; e < 4; ++e) gb[r][e] = bp[(size_t)e * N_DIM];
        }
        const bool mA = (kt >= ktA), mB = (kt < ktB);
        #pragma unroll
        for (int r = 0; r < 4; ++r) {
            const int f = r * 256 + tid;
            const int row = f >> 3, pos = f & 7;
            float v[4] = {ga[r].x, ga[r].y, ga[r].z, ga[r].w};
            if (mA) {
                const int ig = r0 + row, kg = k0 + pos * 4;
                #pragma unroll
                for (int e = 0; e < 4; ++e) v[e] = (kg + e <= ig) ? v[e] : 0.f;
            }
            unsigned h[4], l[4];
            #pragma unroll
            for (int e = 0; e < 4; ++e) split2(v[e], h[e], l[e]);
            *reinterpret_cast<u32x2*>(&AsH[row][pos * 4]) =
                (u32x2){h[0] | (h[1] << 16), h[2] | (h[3] << 16)};
            *reinterpret_cast<u32x2*>(&AsL[row][pos * 4]) =
                (u32x2){l[0] | (l[1] << 16), l[2] | (l[3] << 16)};
        }
        #pragma unroll
        for (int r = 0; r < 4; ++r) {
            const int f = r * 256 + tid;
            const int col = f & 127, kq = (f >> 7) * 4;
            float v[4] = {gb[r][0], gb[r][1], gb[r][2], gb[r][3]};
            if (mB) {
                const int jg = c0 + col, kg = k0 + kq;
                #pragma unroll
                for (int e = 0; e < 4; ++e) v[e] = (jg <= kg + e) ? v[e] : 0.f;
            }
            unsigned h[4], l[4];
            #pragma unroll
            for (int e = 0; e < 4; ++e) split2(v[e], h[e], l[e]);
            *reinterpret_cast<u32x2*>(&BsH[col][kq]) =
                (u32x2){h[0] | (h[1] << 16), h[2] | (h[3] << 16)};
            *reinterpret_cast<u32x2*>(&BsL[col][kq]) =
                (u32x2){l[0] | (l[1] << 16), l[2] | (l[3] << 16)};
        }
        __syncthreads();
        short8 aH[4], aL[4], bH[4], bL[4];
        #pragma unroll
        for (int m = 0; m < 4; ++m) {
            const int row = wm * 64 + m * 16 + l15;
            aH[m] = *reinterpret_cast<const short8*>(&AsH[row][l4 * 8]);
            aL[m] = *reinterpret_cast<const short8*>(&AsL[row][l4 * 8]);
        }
        #pragma unroll
        for (int n = 0; n < 4; ++n) {
            const int col = wn * 64 + n * 16 + l15;
            bH[n] = *reinterpret_cast<const short8*>(&BsH[col][l4 * 8]);
            bL[n] = *reinterpret_cast<const short8*>(&BsL[col][l4 * 8]);
        }
        #pragma unroll
        for (int m = 0; m < 4; ++m)
            #pragma unroll
            for (int n = 0; n < 4; ++n) {
                acc[m][n] = __builtin_amdgcn_mfma_f32_16x16x32_bf16(aH[m], bH[n], acc[m][n], 0, 0, 0);
                acc[m][n] = __builtin_amdgcn_mfma_f32_16x16x32_bf16(aH[m], bL[n], acc[m][n], 0, 0, 0);
                acc[m][n] = __builtin_amdgcn_mfma_f32_16x16x32_bf16(aL[m], bH[n], acc[m][n], 0, 0, 0);
            }
    }
    const bool diag = (bi == bj);
    #pragma unroll
    for (int m = 0; m < 4; ++m) {
        const int i0 = r0 + wm * 64 + m * 16 + l4 * 4;
        #pragma unroll
        for (int n = 0; n < 4; ++n) {
            const int j = c0 + wn * 64 + n * 16 + l15;
            #pragma unroll
            for (int r = 0; r < 4; ++r) {
                float val = acc[m][n][r];
                if (diag && (j > i0 + r)) val = 0.f;
                C[(size_t)(i0 + r) * N_DIM + j] = val;
            }
        }
    }
}

extern "C" void kernel_launch(void* const* d_in, const int* in_sizes, int n_in,
                              void* d_out, int out_size, void* d_ws, size_t ws_size,
                              hipStream_t stream) {
    const float* A = (const float*)d_in[0];
    const float* B = (const float*)d_in[1];
    float* C = (float*)d_out;
    const size_t planeElems = (size_t)N_DIM * N_DIM;
    if (ws_size >= 2 * planeElems * sizeof(unsigned short)) {   // 64 MiB
        unsigned short* Ah = (unsigned short*)d_ws;
        unsigned short* Bt = Ah + planeElems;
        hipMemsetAsync(d_out, 0, planeElems * sizeof(float), stream);
        hipLaunchKernelGGL(split_A1,  dim3(N_LOWER), dim3(256), 0, stream, A, Ah);
        hipLaunchKernelGGL(split_Bt1, dim3(64, 64),  dim3(256), 0, stream, B, Bt);
        hipLaunchKernelGGL(trimm_seg, dim3(N_LOWER, 2), dim3(256), 0, stream,
                           Ah, Bt, C);
    } else {
        hipLaunchKernelGGL(trimm_fallback, dim3(NT * NT), dim3(256), 0, stream, A, B, C);
    }
}

// Round 9
// 228.694 us; speedup vs baseline: 1.0124x; 1.0124x over previous
//
#include <hip/hip_runtime.h>

// C = tril(tril(A) @ tril(B)), N=4096, fp32 in/out.
// Round 9: round-8 pipeline + inline-asm ds_read_b128 fragment reads.
//   Round 7/8 identical timing proved the compiler inserts a conservative
//   s_waitcnt vmcnt(0) before C++ ds_reads of LDS written by global_load_lds
//   (rotating buf index defeats alias analysis). Fix = read fragments via
//   inline asm (compiler loses the dependency; our counted vmcnt(4) + barrier
//   + lgkmcnt(0) + sched_barrier(0) carry correctness — m201/HK pattern).
//   XOR slot (l4^(r>>1))&3 is m-independent -> one base VGPR + offset: imm.
//   Everything else identical to round 8 (verified): memset C, bf16 planes,
//   split-K (2 segs, atomicAdd), both-sides XOR swizzle, 3-buffer pipeline.

typedef __attribute__((ext_vector_type(8))) short short8;   // 8 bf16 (4 VGPR)
typedef __attribute__((ext_vector_type(4))) float f32x4;
typedef __attribute__((ext_vector_type(2))) unsigned int u32x2;
typedef __attribute__((ext_vector_type(4))) unsigned int u32x4;

constexpr int N_DIM = 4096;
constexpr int BM = 128, BN = 128, BK = 32;
constexpr int NT = N_DIM / BM;             // 32
constexpr int N_LOWER = NT * (NT + 1) / 2; // 528

__device__ __forceinline__ unsigned bf16_rne(float x) {
    const unsigned u = __float_as_uint(x);
    return (u + 0x7FFFu + ((u >> 16) & 1u)) >> 16;
}
__device__ __forceinline__ void split2(float x, unsigned& h, unsigned& l) {
    h = bf16_rne(x);
    const float r = x - __uint_as_float(h << 16);
    l = __float_as_uint(r) >> 16;
}
__device__ __forceinline__ void gload_lds16(const void* g, void* l) {
    __builtin_amdgcn_global_load_lds(
        (const __attribute__((address_space(1))) void*)g,
        (__attribute__((address_space(3))) void*)l, 16, 0, 0);
}

// ---------------- P1: Ah = bf16(tril(A)), row-major, lower tiles ----------------
__global__ __launch_bounds__(256)
void split_A1(const float* __restrict__ A, unsigned short* __restrict__ Ah) {
    const int id = blockIdx.x;
    int ti = (int)((sqrtf(8.f * (float)id + 1.f) - 1.f) * 0.5f);
    ti = ti < 0 ? 0 : (ti > NT - 1 ? NT - 1 : ti);
    while (ti * (ti + 1) / 2 > id) --ti;
    while ((ti + 1) * (ti + 2) / 2 <= id) ++ti;
    const int tk = id - ti * (ti + 1) / 2;          // tk <= ti
    const int r0 = ti * 128, k0 = tk * 128;
    const bool dg = (ti == tk);
    const int tid = threadIdx.x;
    #pragma unroll
    for (int it = 0; it < 16; ++it) {
        const int f = it * 256 + tid;
        const int row = f >> 5, c4 = (f & 31) * 4;
        const int i = r0 + row;
        const size_t off = (size_t)i * N_DIM + k0 + c4;
        float4 v = *reinterpret_cast<const float4*>(&A[off]);
        if (dg) {
            if (k0 + c4 + 0 > i) v.x = 0.f;
            if (k0 + c4 + 1 > i) v.y = 0.f;
            if (k0 + c4 + 2 > i) v.z = 0.f;
            if (k0 + c4 + 3 > i) v.w = 0.f;
        }
        *reinterpret_cast<u32x2*>(&Ah[off]) =
            (u32x2){bf16_rne(v.x) | (bf16_rne(v.y) << 16),
                    bf16_rne(v.z) | (bf16_rne(v.w) << 16)};
    }
}

// ------------- P2: Bt = bf16(tril(B))^T [col][k], needed 64-tiles only ----------
__global__ __launch_bounds__(256)
void split_Bt1(const float* __restrict__ B, unsigned short* __restrict__ Bt) {
    const int tk = blockIdx.x, tj = blockIdx.y;     // 64-elem tiles
    if (tk < (tj & ~1)) return;                     // never read by GEMM
    const int k0 = tk * 64, j0 = tj * 64;
    const int tid = threadIdx.x;
    __shared__ float T[64][69];                     // [col][k], padded
    #pragma unroll
    for (int it = 0; it < 4; ++it) {
        const int f = it * 256 + tid;
        const int kr = f >> 4, c4 = (f & 15) * 4;
        const float4 v = *reinterpret_cast<const float4*>(
            &B[(size_t)(k0 + kr) * N_DIM + j0 + c4]);
        T[c4 + 0][kr] = v.x; T[c4 + 1][kr] = v.y;
        T[c4 + 2][kr] = v.z; T[c4 + 3][kr] = v.w;
    }
    __syncthreads();
    #pragma unroll
    for (int it = 0; it < 2; ++it) {
        const int f = it * 256 + tid;
        const int col = f >> 3, kc = (f & 7) * 8;
        const int j = j0 + col;
        unsigned h[8];
        #pragma unroll
        for (int e = 0; e < 8; ++e) {
            float x = T[col][kc + e];
            if (j > k0 + kc + e) x = 0.f;           // tril(B): keep j<=k
            h[e] = bf16_rne(x);
        }
        *reinterpret_cast<u32x4*>(&Bt[(size_t)j * N_DIM + k0 + kc]) =
            (u32x4){h[0] | (h[1] << 16), h[2] | (h[3] << 16),
                    h[4] | (h[5] << 16), h[6] | (h[7] << 16)};
    }
}

// -------- G: split-K, 3-buffer counted-vmcnt pipeline, asm ds_read --------------
__global__ __launch_bounds__(256)
void trimm_seg(const unsigned short* __restrict__ Ah,
               const unsigned short* __restrict__ Bt,
               float* __restrict__ C) {
    const int tid = threadIdx.x;
    const int idx = blockIdx.x;                     // 0..527, heavy-first
    const int seg = blockIdx.y;                     // 0..1

    // heavy-first: dr=0 -> farthest-from-diagonal first
    int dr = (int)((sqrtf(8.f * (float)idx + 1.f) - 1.f) * 0.5f);
    dr = dr < 0 ? 0 : (dr > NT - 1 ? NT - 1 : dr);
    while (dr * (dr + 1) / 2 > idx) --dr;
    while ((dr + 1) * (dr + 2) / 2 <= idx) ++dr;
    const int bj = idx - dr * (dr + 1) / 2;
    const int bi = bj + (NT - 1 - dr);
    const int r0 = bi * BM, c0 = bj * BN;

    const int kt0 = bj * (BN / BK);
    const int kt1 = (bi + 1) * (BM / BK);
    const int len = kt1 - kt0;                      // 4..128 k-tiles
    const int nseg = (len > 64) ? 2 : 1;
    if (seg >= nseg) return;
    int s0 = kt0, s1 = kt1;
    if (nseg == 2) {
        const int mid = kt0 + (len >> 1);
        if (seg == 0) s1 = mid; else s0 = mid;
    }
    // segment length always >= 2 (min tile len = 4)

    __shared__ __align__(16) unsigned short sA[3][BM * BK];   // 3 x 8 KB
    __shared__ __align__(16) unsigned short sB[3][BN * BK];   // 3 x 8 KB

    const int lane = tid & 63, w = tid >> 6;
    const int wm = w >> 1, wn = w & 1;
    const int l15 = lane & 15, l4 = lane >> 4;
    // XOR slot is frag-index-independent: (l4 ^ (r>>1))&3 == (l4 ^ (l15>>1))&3
    const unsigned xsl = (unsigned)(((l4 ^ (l15 >> 1)) & 3) * 16);   // bytes

    f32x4 acc[4][4];
    #pragma unroll
    for (int m = 0; m < 4; ++m)
        #pragma unroll
        for (int n = 0; n < 4; ++n) acc[m][n] = (f32x4){0.f, 0.f, 0.f, 0.f};

    // STAGE(buf, kt): LDS dest linear; source pre-swizzled (involution).
    // Exactly 4 global_load_lds_dwordx4 instructions per thread.
    #define STAGE(buf, kt)                                                        \
        {                                                                         \
            _Pragma("unroll")                                                     \
            for (int g = 0; g < 2; ++g) {                                         \
                const int c = g * 256 + tid;                                      \
                const int row = c >> 2;                                           \
                const int srcslot = (c ^ (row >> 1)) & 3;                         \
                const int ldst = (g * 256 + (tid & 192)) * 8;                     \
                gload_lds16(&Ah[(size_t)(r0 + row) * N_DIM + (kt) * BK + srcslot * 8], \
                            &sA[buf][ldst]);                                      \
                gload_lds16(&Bt[(size_t)(c0 + row) * N_DIM + (kt) * BK + srcslot * 8], \
                            &sB[buf][ldst]);                                      \
            }                                                                     \
        }

    // COMPUTE(buf): asm ds_read_b128 x8 (compiler-invisible LDS dependency;
    // our waits carry correctness), lgkmcnt(0)+sched_barrier (rule #18), MFMA.
    #define COMPUTE(buf)                                                          \
        {                                                                         \
            const unsigned aB = (unsigned)(uintptr_t)(&sA[buf][0]) +              \
                                (unsigned)((wm * 64 + l15) * 64) + xsl;           \
            const unsigned bB = (unsigned)(uintptr_t)(&sB[buf][0]) +              \
                                (unsigned)((wn * 64 + l15) * 64) + xsl;           \
            u32x4 ra0, ra1, ra2, ra3, rb0, rb1, rb2, rb3;                         \
            asm volatile("ds_read_b128 %0, %1 offset:0"    : "=v"(ra0) : "v"(aB)); \
            asm volatile("ds_read_b128 %0, %1 offset:1024" : "=v"(ra1) : "v"(aB)); \
            asm volatile("ds_read_b128 %0, %1 offset:2048" : "=v"(ra2) : "v"(aB)); \
            asm volatile("ds_read_b128 %0, %1 offset:3072" : "=v"(ra3) : "v"(aB)); \
            asm volatile("ds_read_b128 %0, %1 offset:0"    : "=v"(rb0) : "v"(bB)); \
            asm volatile("ds_read_b128 %0, %1 offset:1024" : "=v"(rb1) : "v"(bB)); \
            asm volatile("ds_read_b128 %0, %1 offset:2048" : "=v"(rb2) : "v"(bB)); \
            asm volatile("ds_read_b128 %0, %1 offset:3072" : "=v"(rb3) : "v"(bB)); \
            asm volatile("s_waitcnt lgkmcnt(0)" ::: "memory");                    \
            __builtin_amdgcn_sched_barrier(0);                                    \
            short8 a[4] = {__builtin_bit_cast(short8, ra0),                       \
                           __builtin_bit_cast(short8, ra1),                       \
                           __builtin_bit_cast(short8, ra2),                       \
                           __builtin_bit_cast(short8, ra3)};                      \
            short8 b[4] = {__builtin_bit_cast(short8, rb0),                       \
                           __builtin_bit_cast(short8, rb1),                       \
                           __builtin_bit_cast(short8, rb2),                       \
                           __builtin_bit_cast(short8, rb3)};                      \
            _Pragma("unroll")                                                     \
            for (int m = 0; m < 4; ++m)                                           \
                _Pragma("unroll")                                                 \
                for (int n = 0; n < 4; ++n)                                       \
                    acc[m][n] = __builtin_amdgcn_mfma_f32_16x16x32_bf16(          \
                        a[m], b[n], acc[m][n], 0, 0, 0);                          \
        }

    // prologue: 2 STAGEs in flight (8 outstanding loads per thread)
    STAGE(0, s0);
    STAGE(1, s0 + 1);

    int cur = 0;
    for (int t = s0; t < s1 - 1; ++t) {
        // own STAGE(t) landed; STAGE(t+1)'s 4 loads stay in flight
        asm volatile("s_waitcnt vmcnt(4)" ::: "memory");
        // all waves' STAGE(t) visible; all waves done reading buf[(t-1)%3]
        __builtin_amdgcn_s_barrier();
        __builtin_amdgcn_sched_barrier(0);   // STAGE below must not hoist above
        if (t + 2 < s1) {
            int b2 = cur + 2; if (b2 >= 3) b2 -= 3;
            STAGE(b2, t + 2);
        }
        COMPUTE(cur);
        ++cur; if (cur == 3) cur = 0;
    }
    // epilogue step t = s1-1: drain remaining loads
    asm volatile("s_waitcnt vmcnt(0)" ::: "memory");
    __builtin_amdgcn_s_barrier();
    __builtin_amdgcn_sched_barrier(0);
    COMPUTE(cur);
    #undef STAGE
    #undef COMPUTE

    // epilogue: C/D layout col=l&15, row=(l>>4)*4+reg (m89-verified)
    if (nseg == 1) {
        const bool diag = (bi == bj);
        #pragma unroll
        for (int m = 0; m < 4; ++m) {
            const int i0 = r0 + wm * 64 + m * 16 + l4 * 4;
            #pragma unroll
            for (int n = 0; n < 4; ++n) {
                const int j = c0 + wn * 64 + n * 16 + l15;
                #pragma unroll
                for (int r = 0; r < 4; ++r) {
                    float val = acc[m][n][r];
                    if (diag && (j > i0 + r)) val = 0.f;
                    C[(size_t)(i0 + r) * N_DIM + j] = val;
                }
            }
        }
    } else {
        // 2 segments, C pre-zeroed: exactly 2 fp32 adds/element (deterministic)
        #pragma unroll
        for (int m = 0; m < 4; ++m) {
            const int i0 = r0 + wm * 64 + m * 16 + l4 * 4;
            #pragma unroll
            for (int n = 0; n < 4; ++n) {
                const int j = c0 + wn * 64 + n * 16 + l15;
                #pragma unroll
                for (int r = 0; r < 4; ++r)
                    atomicAdd(&C[(size_t)(i0 + r) * N_DIM + j], acc[m][n][r]);
            }
        }
    }
}

// ---------------- fallback: round-3 kernel (in-loop split bf16x3), verified -----
constexpr int LP = 40;
__global__ __launch_bounds__(256)
void trimm_fallback(const float* __restrict__ A, const float* __restrict__ B,
                    float* __restrict__ C) {
    const int tid = threadIdx.x;
    const int id = blockIdx.x;
    if (id >= N_LOWER) {
        int u = id - N_LOWER, bi = 0;
        while (u >= NT - 1 - bi) { u -= NT - 1 - bi; ++bi; }
        const int bj = bi + 1 + u;
        const int r0 = bi * BM, c0 = bj * BN;
        const float4 z = make_float4(0.f, 0.f, 0.f, 0.f);
        #pragma unroll
        for (int r = 0; r < 16; ++r) {
            const int f = r * 256 + tid;
            *reinterpret_cast<float4*>(
                &C[(size_t)(r0 + (f >> 5)) * N_DIM + c0 + (f & 31) * 4]) = z;
        }
        return;
    }
    int dr = (int)((sqrtf(8.f * (float)id + 1.f) - 1.f) * 0.5f);
    dr = dr < 0 ? 0 : (dr > NT - 1 ? NT - 1 : dr);
    while (dr * (dr + 1) / 2 > id) --dr;
    while ((dr + 1) * (dr + 2) / 2 <= id) ++dr;
    const int bj = id - dr * (dr + 1) / 2;
    const int bi = bj + (NT - 1 - dr);
    const int r0 = bi * BM, c0 = bj * BN;

    __shared__ __align__(16) unsigned short AsH[BM][LP];
    __shared__ __align__(16) unsigned short AsL[BM][LP];
    __shared__ __align__(16) unsigned short BsH[BN][LP];
    __shared__ __align__(16) unsigned short BsL[BN][LP];

    const int lane = tid & 63, w = tid >> 6;
    const int wm = w >> 1, wn = w & 1;
    const int l15 = lane & 15, l4 = lane >> 4;

    f32x4 acc[4][4];
    #pragma unroll
    for (int m = 0; m < 4; ++m)
        #pragma unroll
        for (int n = 0; n < 4; ++n) acc[m][n] = (f32x4){0.f, 0.f, 0.f, 0.f};

    const int kt0 = bj * (BN / BK);
    const int kt1 = (bi + 1) * (BM / BK);
    const int ktA = bi * (BM / BK);
    const int ktB = (bj + 1) * (BN / BK);

    for (int kt = kt0; kt < kt1; ++kt) {
        const int k0 = kt * BK;
        __syncthreads();
        float4 ga[4]; float gb[4][4];
        #pragma unroll
        for (int r = 0; r < 4; ++r) {
            const int f = r * 256 + tid;
            ga[r] = *reinterpret_cast<const float4*>(
                &A[(size_t)(r0 + (f >> 3)) * N_DIM + k0 + (f & 7) * 4]);
        }
        #pragma unroll
        for (int r = 0; r < 4; ++r) {
            const int f = r * 256 + tid;
            const int col = f & 127, kq = (f >> 7) * 4;
            const float* bp = &B[(size_t)(k0 + kq) * N_DIM + c0 + col];
            #pragma unroll
            for (int e = 0; e < 4; ++e) gb[r][e] = bp[(size_t)e * N_DIM];
        }
        const bool mA = (kt >= ktA), mB = (kt < ktB);
        #pragma unroll
        for (int r = 0; r < 4; ++r) {
            const int f = r * 256 + tid;
            const int row = f >> 3, pos = f & 7;
            float v[4] = {ga[r].x, ga[r].y, ga[r].z, ga[r].w};
            if (mA) {
                const int ig = r0 + row, kg = k0 + pos * 4;
                #pragma unroll
                for (int e = 0; e < 4; ++e) v[e] = (kg + e <= ig) ? v[e] : 0.f;
            }
            unsigned h[4], l[4];
            #pragma unroll
            for (int e = 0; e < 4; ++e) split2(v[e], h[e], l[e]);
            *reinterpret_cast<u32x2*>(&AsH[row][pos * 4]) =
                (u32x2){h[0] | (h[1] << 16), h[2] | (h[3] << 16)};
            *reinterpret_cast<u32x2*>(&AsL[row][pos * 4]) =
                (u32x2){l[0] | (l[1] << 16), l[2] | (l[3] << 16)};
        }
        #pragma unroll
        for (int r = 0; r < 4; ++r) {
            const int f = r * 256 + tid;
            const int col = f & 127, kq = (f >> 7) * 4;
            float v[4] = {gb[r][0], gb[r][1], gb[r][2], gb[r][3]};
            if (mB) {
                const int jg = c0 + col, kg = k0 + kq;
                #pragma unroll
                for (int e = 0; e < 4; ++e) v[e] = (jg <= kg + e) ? v[e] : 0.f;
            }
            unsigned h[4], l[4];
            #pragma unroll
            for (int e = 0; e < 4; ++e) split2(v[e], h[e], l[e]);
            *reinterpret_cast<u32x2*>(&BsH[col][kq]) =
                (u32x2){h[0] | (h[1] << 16), h[2] | (h[3] << 16)};
            *reinterpret_cast<u32x2*>(&BsL[col][kq]) =
                (u32x2){l[0] | (l[1] << 16), l[2] | (l[3] << 16)};
        }
        __syncthreads();
        short8 aH[4], aL[4], bH[4], bL[4];
        #pragma unroll
        for (int m = 0; m < 4; ++m) {
            const int row = wm * 64 + m * 16 + l15;
            aH[m] = *reinterpret_cast<const short8*>(&AsH[row][l4 * 8]);
            aL[m] = *reinterpret_cast<const short8*>(&AsL[row][l4 * 8]);
        }
        #pragma unroll
        for (int n = 0; n < 4; ++n) {
            const int col = wn * 64 + n * 16 + l15;
            bH[n] = *reinterpret_cast<const short8*>(&BsH[col][l4 * 8]);
            bL[n] = *reinterpret_cast<const short8*>(&BsL[col][l4 * 8]);
        }
        #pragma unroll
        for (int m = 0; m < 4; ++m)
            #pragma unroll
            for (int n = 0; n < 4; ++n) {
                acc[m][n] = __builtin_amdgcn_mfma_f32_16x16x32_bf16(aH[m], bH[n], acc[m][n], 0, 0, 0);
                acc[m][n] = __builtin_amdgcn_mfma_f32_16x16x32_bf16(aH[m], bL[n], acc[m][n], 0, 0, 0);
                acc[m][n] = __builtin_amdgcn_mfma_f32_16x16x32_bf16(aL[m], bH[n], acc[m][n], 0, 0, 0);
            }
    }
    const bool diag = (bi == bj);
    #pragma unroll
    for (int m = 0; m < 4; ++m) {
        const int i0 = r0 + wm * 64 + m * 16 + l4 * 4;
        #pragma unroll
        for (int n = 0; n < 4; ++n) {
            const int j = c0 + wn * 64 + n * 16 + l15;
            #pragma unroll
            for (int r = 0; r < 4; ++r) {
                float val = acc[m][n][r];
                if (diag && (j > i0 + r)) val = 0.f;
                C[(size_t)(i0 + r) * N_DIM + j] = val;
            }
        }
    }
}

extern "C" void kernel_launch(void* const* d_in, const int* in_sizes, int n_in,
                              void* d_out, int out_size, void* d_ws, size_t ws_size,
                              hipStream_t stream) {
    const float* A = (const float*)d_in[0];
    const float* B = (const float*)d_in[1];
    float* C = (float*)d_out;
    const size_t planeElems = (size_t)N_DIM * N_DIM;
    if (ws_size >= 2 * planeElems * sizeof(unsigned short)) {   // 64 MiB
        unsigned short* Ah = (unsigned short*)d_ws;
        unsigned short* Bt = Ah + planeElems;
        hipMemsetAsync(d_out, 0, planeElems * sizeof(float), stream);
        hipLaunchKernelGGL(split_A1,  dim3(N_LOWER), dim3(256), 0, stream, A, Ah);
        hipLaunchKernelGGL(split_Bt1, dim3(64, 64),  dim3(256), 0, stream, B, Bt);
        hipLaunchKernelGGL(trimm_seg, dim3(N_LOWER, 2), dim3(256), 0, stream,
                           Ah, Bt, C);
    } else {
        hipLaunchKernelGGL(trimm_fallback, dim3(NT * NT), dim3(256), 0, stream, A, B, C);
    }
}